// Round 13
// baseline (2251.157 us; speedup 1.0000x reference)
//
#include <hip/hip_runtime.h>
#include <cstdint>
#include <cstddef>
#include <type_traits>

using u64 = unsigned long long;
using i64 = long long;

#define DEVI __device__ __forceinline__

template <int N, int I = 0, typename F>
DEVI void static_for(F&& f) {
    if constexpr (I < N) {
        f(std::integral_constant<int, I>{});
        static_for<N, I + 1>((F&&)f);
    }
}

// ---------------------------------------------------------------- reductions
DEVI double waveRed(double v) {
    #pragma unroll
    for (int o = 32; o > 0; o >>= 1) v += __shfl_down(v, o, 64);
    return v;
}

// ---------------------------------------------------------------- conv0 stats (np-f32: FMA chain, (kh,kw,ci) order)
__global__ __launch_bounds__(256, 1) void conv0_sums3(const float* __restrict__ x,
                                                      const float* __restrict__ w0,
                                                      double* __restrict__ sum,
                                                      double* __restrict__ sumsq) {
    __shared__ float xs[3072];
    __shared__ float wsh[864];          // 32 co * 27, tap-major
    __shared__ double redS[4][32], redS2[4][32];
    int tid = threadIdx.x, n = blockIdx.y, co0 = blockIdx.x * 32;
    for (int i = tid; i < 3072; i += 256) xs[i] = x[n * 3072 + i];
    for (int i = tid; i < 864; i += 256) {
        int co = i / 27, j = i % 27;    // j = tap-major (kh*3+kw)*3 + ci
        int ci = j % 3, k = j / 3;
        wsh[i] = w0[(co0 + co) * 27 + ci * 9 + k];
    }
    __syncthreads();

    float xv[4][27];
    #pragma unroll
    for (int k = 0; k < 4; ++k) {
        int pos = tid + k * 256, h = pos >> 5, w = pos & 31;
        #pragma unroll
        for (int kh = 0; kh < 3; ++kh) {
            #pragma unroll
            for (int kw = 0; kw < 3; ++kw) {
                #pragma unroll
                for (int ci = 0; ci < 3; ++ci) {
                    int ih = h + kh - 1, iw = w + kw - 1;
                    bool ok = (unsigned)ih < 32u && (unsigned)iw < 32u;
                    xv[k][(kh * 3 + kw) * 3 + ci] = ok ? xs[ci * 1024 + ih * 32 + iw] : 0.0f;
                }
            }
        }
    }
    int lane = tid & 63, wv = tid >> 6;
    for (int co = 0; co < 32; ++co) {
        #pragma clang fp contract(off)
        const float* wp = &wsh[co * 27];
        float a0 = 0.f, a1 = 0.f, a2 = 0.f, a3 = 0.f;
        #pragma unroll
        for (int j = 0; j < 27; ++j) {
            float wj = wp[j];
            a0 = __builtin_fmaf(xv[0][j], wj, a0);
            a1 = __builtin_fmaf(xv[1][j], wj, a1);
            a2 = __builtin_fmaf(xv[2][j], wj, a2);
            a3 = __builtin_fmaf(xv[3][j], wj, a3);
        }
        double y0 = a0, y1 = a1, y2 = a2, y3 = a3;
        double s  = (y0 + y1) + (y2 + y3);
        double s2 = (y0 * y0 + y1 * y1) + (y2 * y2 + y3 * y3);
        s = waveRed(s); s2 = waveRed(s2);
        if (lane == 0) { redS[wv][co] = s; redS2[wv][co] = s2; }
    }
    __syncthreads();
    if (tid < 32) {
        atomicAdd(&sum[co0 + tid], (redS[0][tid] + redS[1][tid]) + (redS[2][tid] + redS[3][tid]));
    } else if (tid < 64) {
        int c = tid - 32;
        atomicAdd(&sumsq[co0 + c], (redS2[0][c] + redS2[1][c]) + (redS2[2][c] + redS2[3][c]));
    }
}

__global__ void finalize_c0(const double* __restrict__ sum, const double* __restrict__ sumsq,
                            const float* __restrict__ g, const float* __restrict__ b,
                            double* __restrict__ M, double* __restrict__ A,
                            double* __restrict__ BB) {
    int c = threadIdx.x;    // 128
    double m = sum[c] / 262144.0;
    double var = sumsq[c] / 262144.0 - m * m;
    M[c]  = m;
    A[c]  = (double)g[c] / sqrt(var + 1e-5);
    BB[c] = (double)b[c];
}

// ---------------------------------------------------------------- conv0 pack
__global__ __launch_bounds__(256, 1) void conv0_pack3(const float* __restrict__ x,
                                                      const float* __restrict__ w0,
                                                      const double* __restrict__ M,
                                                      const double* __restrict__ A,
                                                      const double* __restrict__ BB,
                                                      u64* __restrict__ A0) {
    __shared__ float xs[3072];
    __shared__ float wsh[3456];
    __shared__ double msh[128], ash[128], bsh[128];
    int tid = threadIdx.x, n = blockIdx.x >> 2;
    int pos = ((blockIdx.x & 3) << 8) + tid;
    for (int i = tid; i < 3072; i += 256) xs[i] = x[n * 3072 + i];
    for (int i = tid; i < 3456; i += 256) {
        int co = i / 27, j = i % 27;    // tap-major
        int ci = j % 3, k = j / 3;
        wsh[i] = w0[co * 27 + ci * 9 + k];
    }
    if (tid < 128) { msh[tid] = M[tid]; ash[tid] = A[tid]; bsh[tid] = BB[tid]; }
    __syncthreads();

    int h = pos >> 5, w = pos & 31;
    float xv[27];
    #pragma unroll
    for (int kh = 0; kh < 3; ++kh) {
        #pragma unroll
        for (int kw = 0; kw < 3; ++kw) {
            #pragma unroll
            for (int ci = 0; ci < 3; ++ci) {
                int ih = h + kh - 1, iw = w + kw - 1;
                bool ok = (unsigned)ih < 32u && (unsigned)iw < 32u;
                xv[(kh * 3 + kw) * 3 + ci] = ok ? xs[ci * 1024 + ih * 32 + iw] : 0.0f;
            }
        }
    }
    u64 b0 = 0, b1 = 0;
    #pragma unroll 4
    for (int co = 0; co < 128; ++co) {
        #pragma clang fp contract(off)
        float acc = 0.f;
        const float* wp = &wsh[co * 27];
        #pragma unroll
        for (int j = 0; j < 27; ++j) acc = __builtin_fmaf(xv[j], wp[j], acc);
        double t = ash[co] * ((double)acc - msh[co]) + bsh[co];
        u64 bit = t > 0.0 ? 1ull : 0ull;
        if (co < 64) b0 |= bit << co; else b1 |= bit << (co - 64);
    }
    size_t p = (size_t)n * 1024 + pos;
    A0[p * 2] = b0; A0[p * 2 + 1] = b1;
}

// ---------------------------------------------------------------- weight bit-pack
__global__ __launch_bounds__(256) void pack_w(const float* __restrict__ w,
                                              u64* __restrict__ Wb, int Ci, int Co) {
    int widx = blockIdx.x * 4 + (threadIdx.x >> 6);
    int lane = threadIdx.x & 63;
    int CW = Ci >> 6;
    int co = widx % Co;
    int rest = widx / Co;
    int cw = rest % CW;
    int k = rest / CW;
    int kh = k / 3, kw = k % 3;
    int ci = (cw << 6) | lane;
    float v = w[((size_t)(co * Ci + ci) * 3 + kh) * 3 + kw];
    u64 m = __ballot(v > 0.0f);
    if (lane == 0) Wb[widx] = m;
}

// ---------------------------------------------------------------- bit binary conv, STATIC sliding register tile
// Thread = (n, ho-row, co); covers the full output row. Window tile shifts by
// static register moves; all indices compile-time (static_for) -> no scratch.
// Row validity is wave-uniform runtime predicate. nv analytic. Fused BN stats.
template <int CW, int CO, int HI, bool POOL>
__global__ __launch_bounds__(256, 2)
void bconv_bits5(const u64* __restrict__ A, const u64* __restrict__ Wb,
                 short* __restrict__ dots, i64* __restrict__ sums) {
    constexpr int WI = HI;
    constexpr int HO = POOL ? HI / 2 : HI;
    constexpr int WO = POOL ? WI / 2 : WI;
    constexpr int ROWS = POOL ? 4 : 3;
    constexpr int COLS = POOL ? 4 : 3;
    constexpr int SH = POOL ? 2 : 1;
    constexpr int CH = CW / 2;
    constexpr int NC = POOL ? 4 : 1;
    constexpr int PCN = (CH > 1) ? WO * NC : 1;

    int gid = blockIdx.x * 256 + threadIdx.x;
    int co = gid % CO;
    int rest = gid / CO;            // wave-uniform (CO multiple of 64)
    int ho = rest % HO;
    int n = rest / HO;
    int hbase = (POOL ? 2 * ho : ho) - 1;

    const u64* An = A + (size_t)n * HI * WI * CW;

    bool rv[ROWS];
    #pragma unroll
    for (int r = 0; r < ROWS; ++r) rv[r] = (unsigned)(hbase + r) < (unsigned)HI;

    u64 tile[ROWS][COLS][2];
    u64 wch[18];
    int pcacc[PCN];
    #pragma unroll
    for (int i = 0; i < PCN; ++i) pcacc[i] = 0;

    int s = 0, s2 = 0;

    #pragma unroll
    for (int ch = 0; ch < CH; ++ch) {
        #pragma unroll
        for (int k = 0; k < 9; ++k) {
            wch[2 * k]     = Wb[(size_t)(k * CW + 2 * ch)     * CO + co];
            wch[2 * k + 1] = Wb[(size_t)(k * CW + 2 * ch + 1) * CO + co];
        }
        static_for<WO>([&](auto woc) {
            constexpr int wo = decltype(woc)::value;
            constexpr int wbase = POOL ? 2 * wo : wo;
            // ---- load / slide (all column indices static) ----
            if constexpr (wo == 0) {
                static_for<COLS>([&](auto cc) {
                    constexpr int c = decltype(cc)::value;
                    constexpr int iw = wbase - 1 + c;
                    if constexpr (iw >= 0 && iw < WI) {
                        #pragma unroll
                        for (int r = 0; r < ROWS; ++r) if (rv[r]) {
                            const ulonglong2* p = (const ulonglong2*)
                                (An + (size_t)((hbase + r) * WI + iw) * CW + 2 * ch);
                            ulonglong2 v = *p;
                            tile[r][c][0] = v.x; tile[r][c][1] = v.y;
                        }
                    }
                });
            } else {
                #pragma unroll
                for (int r = 0; r < ROWS; ++r)
                    static_for<COLS - SH>([&](auto cc) {
                        constexpr int c = decltype(cc)::value;
                        tile[r][c][0] = tile[r][c + SH][0];
                        tile[r][c][1] = tile[r][c + SH][1];
                    });
                static_for<SH>([&](auto scc) {
                    constexpr int c = COLS - SH + decltype(scc)::value;
                    constexpr int iw = wbase - 1 + c;
                    if constexpr (iw >= 0 && iw < WI) {
                        #pragma unroll
                        for (int r = 0; r < ROWS; ++r) if (rv[r]) {
                            const ulonglong2* p = (const ulonglong2*)
                                (An + (size_t)((hbase + r) * WI + iw) * CW + 2 * ch);
                            ulonglong2 v = *p;
                            tile[r][c][0] = v.x; tile[r][c][1] = v.y;
                        }
                    }
                });
            }
            // ---- candidates (static tap indices, runtime row predicates) ----
            int pcs[NC];
            static_for<NC>([&](auto cdc) {
                constexpr int cd = decltype(cdc)::value;
                constexpr int py = POOL ? (cd >> 1) : 0;
                constexpr int px = POOL ? (cd & 1) : 0;
                int pc = 0;
                static_for<3>([&](auto khc) {
                    constexpr int kh = decltype(khc)::value;
                    constexpr int r = py + kh;
                    static_for<3>([&](auto kwc) {
                        constexpr int kw = decltype(kwc)::value;
                        constexpr int iw = wbase + px + kw - 1;
                        constexpr int c = px + kw;
                        if constexpr (iw >= 0 && iw < WI) {
                            int add = __popcll(tile[r][c][0] ^ wch[(kh * 3 + kw) * 2])
                                    + __popcll(tile[r][c][1] ^ wch[(kh * 3 + kw) * 2 + 1]);
                            pc += rv[r] ? add : 0;
                        }
                    });
                });
                pcs[cd] = pc;
            });
            if constexpr (CH > 1) {
                static_for<NC>([&](auto cdc) {
                    constexpr int cd = decltype(cdc)::value;
                    pcacc[wo * NC + cd] += pcs[cd];
                });
            } else {
                int best;
                if constexpr (POOL) {
                    best = -(1 << 30);
                    static_for<4>([&](auto cdc) {
                        constexpr int cd = decltype(cdc)::value;
                        constexpr int py = cd >> 1, px = cd & 1;
                        constexpr int wc = 0;  (void)wc;
                        int hc = 2 * ho + py;
                        constexpr int wcc = 2 * wo + px;
                        int vr = 3 - (hc == 0) - (hc == HI - 1);
                        constexpr int vc = 3 - (wcc == 0 ? 1 : 0) - (wcc == WI - 1 ? 1 : 0);
                        int dot = vr * vc * CW * 64 - 2 * pcs[cd];
                        best = dot > best ? dot : best;
                    });
                } else {
                    int vr = 3 - (ho == 0) - (ho == HI - 1);
                    constexpr int vc = 3 - (wo == 0 ? 1 : 0) - (wo == WI - 1 ? 1 : 0);
                    best = vr * vc * CW * 64 - 2 * pcs[0];
                }
                dots[(size_t)((n * HO + ho) * WO + wo) * CO + co] = (short)best;
                s += best; s2 += best * best;
            }
        });
    }

    if constexpr (CH > 1) {
        static_for<WO>([&](auto woc) {
            constexpr int wo = decltype(woc)::value;
            int best;
            if constexpr (POOL) {
                best = -(1 << 30);
                static_for<4>([&](auto cdc) {
                    constexpr int cd = decltype(cdc)::value;
                    constexpr int py = cd >> 1, px = cd & 1;
                    int hc = 2 * ho + py;
                    constexpr int wcc = 2 * wo + px;
                    int vr = 3 - (hc == 0) - (hc == HI - 1);
                    constexpr int vc = 3 - (wcc == 0 ? 1 : 0) - (wcc == WI - 1 ? 1 : 0);
                    int dot = vr * vc * CW * 64 - 2 * pcacc[wo * 4 + cd];
                    best = dot > best ? dot : best;
                });
            } else {
                int vr = 3 - (ho == 0) - (ho == HI - 1);
                constexpr int vc = 3 - (wo == 0 ? 1 : 0) - (wo == WI - 1 ? 1 : 0);
                best = vr * vc * CW * 64 - 2 * pcacc[wo];
            }
            dots[(size_t)((n * HO + ho) * WO + wo) * CO + co] = (short)best;
            s += best; s2 += best * best;
        });
    }

    atomicAdd((u64*)&sums[co], (u64)(i64)s);
    atomicAdd((u64*)&sums[CO + co], (u64)(i64)s2);
}

__global__ void finalize_bn(const i64* __restrict__ sums,
                            const float* __restrict__ g, const float* __restrict__ b,
                            int CO, double cnt, double* __restrict__ M,
                            double* __restrict__ A, double* __restrict__ BB) {
    int c = blockIdx.x * blockDim.x + threadIdx.x;
    if (c >= CO) return;
    double m = (double)sums[c] / cnt;
    double var = (double)sums[CO + c] / cnt - m * m;
    M[c]  = m;
    A[c]  = (double)g[c] / sqrt(var + 1e-5);
    BB[c] = (double)b[c];
}

// ---------------------------------------------------------------- binarize + bit-pack
template <int CO>
__global__ __launch_bounds__(256) void binpack_k(const short* __restrict__ xin,
                                                 const double* __restrict__ M,
                                                 const double* __restrict__ A,
                                                 const double* __restrict__ BB,
                                                 u64* __restrict__ Ab) {
    constexpr int CWo = CO / 64;
    int widx = blockIdx.x * 4 + (threadIdx.x >> 6);
    int lane = threadIdx.x & 63;
    int w = widx & (CWo - 1);
    int p = widx / CWo;
    int c = (w << 6) | lane;
    double t = A[c] * ((double)xin[(size_t)p * CO + c] - M[c]) + BB[c];
    u64 m = __ballot(t > 0.0);
    if (lane == 0) Ab[widx] = m;
}

// ---------------------------------------------------------------- FC head
__global__ __launch_bounds__(256) void fc_k(const short* __restrict__ x5,
                                            const double* __restrict__ M,
                                            const double* __restrict__ A,
                                            const double* __restrict__ BB,
                                            const float* __restrict__ wfc,
                                            const float* __restrict__ bfc,
                                            float* __restrict__ out) {
    int n = blockIdx.x / 10, k = blockIdx.x % 10;
    double acc = 0.0;
    for (int i = threadIdx.x; i < 8192; i += 256) {
        int c = i >> 4, hw = i & 15, h = hw >> 2, ww = hw & 3;
        double t = A[c] * ((double)x5[(size_t)((n * 4 + h) * 4 + ww) * 512 + c] - M[c]) + BB[c];
        t = t < -1.0 ? -1.0 : (t > 1.0 ? 1.0 : t);
        acc += t * (double)wfc[(size_t)k * 8192 + i];
    }
    acc = waveRed(acc);
    __shared__ double sd[4];
    if ((threadIdx.x & 63) == 0) sd[threadIdx.x >> 6] = acc;
    __syncthreads();
    if (threadIdx.x == 0)
        out[n * 10 + k] = (float)(sd[0] + sd[1] + sd[2] + sd[3] + (double)bfc[k]);
}

// ---------------------------------------------------------------- launch
extern "C" void kernel_launch(void* const* d_in, const int* in_sizes, int n_in,
                              void* d_out, int out_size, void* d_ws, size_t ws_size,
                              hipStream_t stream) {
    (void)in_sizes; (void)n_in; (void)out_size; (void)ws_size;

    const float* x   = (const float*)d_in[0];
    const float* w0  = (const float*)d_in[1];
    const float* g0  = (const float*)d_in[2];
    const float* b0  = (const float*)d_in[3];
    const float* w1  = (const float*)d_in[4];
    const float* g1  = (const float*)d_in[5];
    const float* b1  = (const float*)d_in[6];
    const float* w2  = (const float*)d_in[7];
    const float* g2  = (const float*)d_in[8];
    const float* b2  = (const float*)d_in[9];
    const float* w3  = (const float*)d_in[10];
    const float* g3  = (const float*)d_in[11];
    const float* b3  = (const float*)d_in[12];
    const float* w4  = (const float*)d_in[13];
    const float* g4  = (const float*)d_in[14];
    const float* b4  = (const float*)d_in[15];
    const float* w5  = (const float*)d_in[16];
    const float* g5  = (const float*)d_in[17];
    const float* b5  = (const float*)d_in[18];
    const float* wfc = (const float*)d_in[19];
    const float* bfc = (const float*)d_in[20];
    float* out = (float*)d_out;

    // ---- workspace layout (~43.2 MB) ----
    char* ws = (char*)d_ws;
    double* sum0   = (double*)ws;                  // 128
    double* sumsq0 = sum0 + 128;                   // 128
    i64* isums = (i64*)(sumsq0 + 128);             // 5 layers * 1024
    // zero span: 2048 + 40960 = 43008 bytes
    double* M  = (double*)(ws + 65536);            // 6*512
    double* A  = M + 3072;
    double* BB = A + 3072;
    char* p = ws + 65536 + 73728;
    u64* A0 = (u64*)p;  p += (size_t)262144 * 2 * 8;   // 4 MiB
    u64* A1 = (u64*)p;  p += (size_t)65536 * 2 * 8;    // 1 MiB
    u64* A2 = (u64*)p;  p += (size_t)65536 * 4 * 8;    // 2 MiB
    u64* A3 = (u64*)p;  p += (size_t)16384 * 4 * 8;    // 0.5 MiB
    u64* A4 = (u64*)p;  p += (size_t)16384 * 8 * 8;    // 1 MiB
    u64* Wb1 = (u64*)p; p += 2304 * 8;
    u64* Wb2 = (u64*)p; p += 4608 * 8;
    u64* Wb3 = (u64*)p; p += 9216 * 8;
    u64* Wb4 = (u64*)p; p += 18432 * 8;
    u64* Wb5 = (u64*)p; p += 36864 * 8;
    p = (char*)(((uintptr_t)p + 255) & ~(uintptr_t)255);
    short* dots = (short*)p;                       // max 65536*256*2 = 33.5 MB

    hipMemsetAsync(d_ws, 0, 43008, stream);

    // weight bit-packs
    pack_w<<<576,  256, 0, stream>>>(w1, Wb1, 128, 128);
    pack_w<<<1152, 256, 0, stream>>>(w2, Wb2, 128, 256);
    pack_w<<<2304, 256, 0, stream>>>(w3, Wb3, 256, 256);
    pack_w<<<4608, 256, 0, stream>>>(w4, Wb4, 256, 512);
    pack_w<<<9216, 256, 0, stream>>>(w5, Wb5, 512, 512);

    // conv0 (np-f32 FMA (kh,kw,ci)) + BN0 + pack
    conv0_sums3<<<dim3(4, 256), 256, 0, stream>>>(x, w0, sum0, sumsq0);
    finalize_c0<<<1, 128, 0, stream>>>(sum0, sumsq0, g0, b0, M, A, BB);
    conv0_pack3<<<1024, 256, 0, stream>>>(x, w0, M, A, BB, A0);

    // L1: 128->128 @32x32, pool -> 16x16
    bconv_bits5<2, 128, 32, true><<<2048, 256, 0, stream>>>(A0, Wb1, dots, isums);
    finalize_bn<<<1, 128, 0, stream>>>(isums, g1, b1, 128, 65536.0, M + 512, A + 512, BB + 512);
    binpack_k<128><<<32768, 256, 0, stream>>>(dots, M + 512, A + 512, BB + 512, A1);

    // L2: 128->256 @16x16
    bconv_bits5<2, 256, 16, false><<<4096, 256, 0, stream>>>(A1, Wb2, dots, isums + 1024);
    finalize_bn<<<1, 256, 0, stream>>>(isums + 1024, g2, b2, 256, 65536.0, M + 1024, A + 1024, BB + 1024);
    binpack_k<256><<<65536, 256, 0, stream>>>(dots, M + 1024, A + 1024, BB + 1024, A2);

    // L3: 256->256 @16x16, pool -> 8x8
    bconv_bits5<4, 256, 16, true><<<2048, 256, 0, stream>>>(A2, Wb3, dots, isums + 2048);
    finalize_bn<<<1, 256, 0, stream>>>(isums + 2048, g3, b3, 256, 16384.0, M + 1536, A + 1536, BB + 1536);
    binpack_k<256><<<16384, 256, 0, stream>>>(dots, M + 1536, A + 1536, BB + 1536, A3);

    // L4: 256->512 @8x8
    bconv_bits5<4, 512, 8, false><<<4096, 256, 0, stream>>>(A3, Wb4, dots, isums + 3072);
    finalize_bn<<<1, 512, 0, stream>>>(isums + 3072, g4, b4, 512, 16384.0, M + 2048, A + 2048, BB + 2048);
    binpack_k<512><<<32768, 256, 0, stream>>>(dots, M + 2048, A + 2048, BB + 2048, A4);

    // L5: 512->512 @8x8, pool -> 4x4
    bconv_bits5<8, 512, 8, true><<<2048, 256, 0, stream>>>(A4, Wb5, dots, isums + 4096);
    finalize_bn<<<1, 512, 0, stream>>>(isums + 4096, g5, b5, 512, 4096.0, M + 2560, A + 2560, BB + 2560);

    // FC head
    fc_k<<<2560, 256, 0, stream>>>(dots, M + 2560, A + 2560, BB + 2560, wfc, bfc, out);
}

// Round 14
// 990.909 us; speedup vs baseline: 2.2718x; 2.2718x over previous
//
#include <hip/hip_runtime.h>
#include <cstdint>
#include <cstddef>

using u64 = unsigned long long;
using i64 = long long;

#define DEVI __device__ __forceinline__

// ---------------------------------------------------------------- reductions
DEVI double waveRed(double v) {
    #pragma unroll
    for (int o = 32; o > 0; o >>= 1) v += __shfl_down(v, o, 64);
    return v;
}

// ---------------------------------------------------------------- conv0 stats (np-f32: FMA chain, (kh,kw,ci) order)
__global__ __launch_bounds__(256, 1) void conv0_sums3(const float* __restrict__ x,
                                                      const float* __restrict__ w0,
                                                      double* __restrict__ sum,
                                                      double* __restrict__ sumsq) {
    __shared__ float xs[3072];
    __shared__ float wsh[864];          // 32 co * 27, tap-major
    __shared__ double redS[4][32], redS2[4][32];
    int tid = threadIdx.x, n = blockIdx.y, co0 = blockIdx.x * 32;
    for (int i = tid; i < 3072; i += 256) xs[i] = x[n * 3072 + i];
    for (int i = tid; i < 864; i += 256) {
        int co = i / 27, j = i % 27;    // j = tap-major (kh*3+kw)*3 + ci
        int ci = j % 3, k = j / 3;
        wsh[i] = w0[(co0 + co) * 27 + ci * 9 + k];
    }
    __syncthreads();

    float xv[4][27];
    #pragma unroll
    for (int k = 0; k < 4; ++k) {
        int pos = tid + k * 256, h = pos >> 5, w = pos & 31;
        #pragma unroll
        for (int kh = 0; kh < 3; ++kh) {
            #pragma unroll
            for (int kw = 0; kw < 3; ++kw) {
                #pragma unroll
                for (int ci = 0; ci < 3; ++ci) {
                    int ih = h + kh - 1, iw = w + kw - 1;
                    bool ok = (unsigned)ih < 32u && (unsigned)iw < 32u;
                    xv[k][(kh * 3 + kw) * 3 + ci] = ok ? xs[ci * 1024 + ih * 32 + iw] : 0.0f;
                }
            }
        }
    }
    int lane = tid & 63, wv = tid >> 6;
    for (int co = 0; co < 32; ++co) {
        #pragma clang fp contract(off)
        const float* wp = &wsh[co * 27];
        float a0 = 0.f, a1 = 0.f, a2 = 0.f, a3 = 0.f;
        #pragma unroll
        for (int j = 0; j < 27; ++j) {
            float wj = wp[j];
            a0 = __builtin_fmaf(xv[0][j], wj, a0);
            a1 = __builtin_fmaf(xv[1][j], wj, a1);
            a2 = __builtin_fmaf(xv[2][j], wj, a2);
            a3 = __builtin_fmaf(xv[3][j], wj, a3);
        }
        double y0 = a0, y1 = a1, y2 = a2, y3 = a3;
        double s  = (y0 + y1) + (y2 + y3);
        double s2 = (y0 * y0 + y1 * y1) + (y2 * y2 + y3 * y3);
        s = waveRed(s); s2 = waveRed(s2);
        if (lane == 0) { redS[wv][co] = s; redS2[wv][co] = s2; }
    }
    __syncthreads();
    if (tid < 32) {
        atomicAdd(&sum[co0 + tid], (redS[0][tid] + redS[1][tid]) + (redS[2][tid] + redS[3][tid]));
    } else if (tid < 64) {
        int c = tid - 32;
        atomicAdd(&sumsq[co0 + c], (redS2[0][c] + redS2[1][c]) + (redS2[2][c] + redS2[3][c]));
    }
}

__global__ void finalize_c0(const double* __restrict__ sum, const double* __restrict__ sumsq,
                            const float* __restrict__ g, const float* __restrict__ b,
                            double* __restrict__ M, double* __restrict__ A,
                            double* __restrict__ BB) {
    int c = threadIdx.x;    // 128
    double m = sum[c] / 262144.0;
    double var = sumsq[c] / 262144.0 - m * m;
    M[c]  = m;
    A[c]  = (double)g[c] / sqrt(var + 1e-5);
    BB[c] = (double)b[c];
}

// ---------------------------------------------------------------- conv0 pack
__global__ __launch_bounds__(256, 1) void conv0_pack3(const float* __restrict__ x,
                                                      const float* __restrict__ w0,
                                                      const double* __restrict__ M,
                                                      const double* __restrict__ A,
                                                      const double* __restrict__ BB,
                                                      u64* __restrict__ A0) {
    __shared__ float xs[3072];
    __shared__ float wsh[3456];
    __shared__ double msh[128], ash[128], bsh[128];
    int tid = threadIdx.x, n = blockIdx.x >> 2;
    int pos = ((blockIdx.x & 3) << 8) + tid;
    for (int i = tid; i < 3072; i += 256) xs[i] = x[n * 3072 + i];
    for (int i = tid; i < 3456; i += 256) {
        int co = i / 27, j = i % 27;    // tap-major
        int ci = j % 3, k = j / 3;
        wsh[i] = w0[co * 27 + ci * 9 + k];
    }
    if (tid < 128) { msh[tid] = M[tid]; ash[tid] = A[tid]; bsh[tid] = BB[tid]; }
    __syncthreads();

    int h = pos >> 5, w = pos & 31;
    float xv[27];
    #pragma unroll
    for (int kh = 0; kh < 3; ++kh) {
        #pragma unroll
        for (int kw = 0; kw < 3; ++kw) {
            #pragma unroll
            for (int ci = 0; ci < 3; ++ci) {
                int ih = h + kh - 1, iw = w + kw - 1;
                bool ok = (unsigned)ih < 32u && (unsigned)iw < 32u;
                xv[(kh * 3 + kw) * 3 + ci] = ok ? xs[ci * 1024 + ih * 32 + iw] : 0.0f;
            }
        }
    }
    u64 b0 = 0, b1 = 0;
    #pragma unroll 4
    for (int co = 0; co < 128; ++co) {
        #pragma clang fp contract(off)
        float acc = 0.f;
        const float* wp = &wsh[co * 27];
        #pragma unroll
        for (int j = 0; j < 27; ++j) acc = __builtin_fmaf(xv[j], wp[j], acc);
        double t = ash[co] * ((double)acc - msh[co]) + bsh[co];
        u64 bit = t > 0.0 ? 1ull : 0ull;
        if (co < 64) b0 |= bit << co; else b1 |= bit << (co - 64);
    }
    size_t p = (size_t)n * 1024 + pos;
    A0[p * 2] = b0; A0[p * 2 + 1] = b1;
}

// ---------------------------------------------------------------- weight bit-pack
__global__ __launch_bounds__(256) void pack_w(const float* __restrict__ w,
                                              u64* __restrict__ Wb, int Ci, int Co) {
    int widx = blockIdx.x * 4 + (threadIdx.x >> 6);
    int lane = threadIdx.x & 63;
    int CW = Ci >> 6;
    int co = widx % Co;
    int rest = widx / Co;
    int cw = rest % CW;
    int k = rest / CW;
    int kh = k / 3, kw = k % 3;
    int ci = (cw << 6) | lane;
    float v = w[((size_t)(co * Ci + ci) * 3 + kh) * 3 + kw];
    u64 m = __ballot(v > 0.0f);
    if (lane == 0) Wb[widx] = m;
}

// ---------------------------------------------------------------- bit binary conv (R11 proven kernel)
template <int CW, int CO, int HI, bool POOL>
__global__ __launch_bounds__(256, 2) void bconv_bits3(const u64* __restrict__ A,
                                                      const u64* __restrict__ Wb,
                                                      short* __restrict__ dots,
                                                      i64* __restrict__ sums) {
    constexpr int WI = HI;
    constexpr int HO = POOL ? HI / 2 : HI;
    constexpr int WO = HO;
    int gid = blockIdx.x * 256 + threadIdx.x;
    int co = gid % CO;
    int rest = gid / CO;
    int ho = rest % HO;
    int n = rest / HO;

    u64 wreg[9 * CW];
    #pragma unroll
    for (int t = 0; t < 9 * CW; ++t) wreg[t] = Wb[(size_t)t * CO + co];

    const u64* An = A + (size_t)n * HI * WI * CW;
    int s = 0, s2 = 0;
    #pragma unroll 2
    for (int wo = 0; wo < WO; ++wo) {
        int best = -(1 << 30);
        #pragma unroll
        for (int py = 0; py < (POOL ? 2 : 1); ++py) {
            #pragma unroll
            for (int px = 0; px < (POOL ? 2 : 1); ++px) {
                int hc = POOL ? 2 * ho + py : ho;
                int wc = POOL ? 2 * wo + px : wo;
                int pc = 0, nv = 0;
                #pragma unroll
                for (int kh = 0; kh < 3; ++kh) {
                    int ih = hc + kh - 1;
                    if ((unsigned)ih >= (unsigned)HI) continue;
                    #pragma unroll
                    for (int kw = 0; kw < 3; ++kw) {
                        int iw = wc + kw - 1;
                        if ((unsigned)iw >= (unsigned)WI) continue;
                        const ulonglong2* ap =
                            (const ulonglong2*)(An + (size_t)(ih * WI + iw) * CW);
                        #pragma unroll
                        for (int cw = 0; cw < CW / 2; ++cw) {
                            ulonglong2 v = ap[cw];
                            pc += __popcll(v.x ^ wreg[(kh * 3 + kw) * CW + 2 * cw])
                                + __popcll(v.y ^ wreg[(kh * 3 + kw) * CW + 2 * cw + 1]);
                        }
                        nv += CW * 64;
                    }
                }
                int dot = nv - 2 * pc;
                best = dot > best ? dot : best;
            }
        }
        dots[(size_t)((n * HO + ho) * WO + wo) * CO + co] = (short)best;
        s += best;
        s2 += best * best;
    }
    atomicAdd((u64*)&sums[co], (u64)(i64)s);
    atomicAdd((u64*)&sums[CO + co], (u64)(i64)s2);
}

// ---------------------------------------------------------------- pooled bconv, window-shared tap loads
// Thread = (n, ho, co). Per (wo, chunk): load the 4x4 union window (16 taps,
// 2 words each) ONCE, compute all 4 pool candidates from it. No cross-iteration
// register state; all arrays constant-indexed inside #pragma unroll loops.
// Boundary taps: clamped addresses + (add & mask) zeroing; nv analytic.
template <int CW, int CO, int HI>
__global__ __launch_bounds__(256, 2) void bconv_pool(const u64* __restrict__ A,
                                                     const u64* __restrict__ Wb,
                                                     short* __restrict__ dots,
                                                     i64* __restrict__ sums) {
    constexpr int WI = HI, HO = HI / 2, WO = WI / 2, CH = CW / 2;
    int gid = blockIdx.x * 256 + threadIdx.x;
    int co = gid % CO;
    int rest = gid / CO;
    int ho = rest % HO;
    int n = rest / HO;
    int hbase = 2 * ho - 1;
    const u64* An = A + (size_t)n * HI * WI * CW;

    int rmask[4];
    const u64* rowp[4];
    #pragma unroll
    for (int r = 0; r < 4; ++r) {
        int ih = hbase + r;
        rmask[r] = ((unsigned)ih < (unsigned)HI) ? -1 : 0;
        int ihc = ih < 0 ? 0 : (ih > HI - 1 ? HI - 1 : ih);
        rowp[r] = An + (size_t)ihc * WI * CW;
    }

    u64 wreg[9 * CW];
    #pragma unroll
    for (int t = 0; t < 9 * CW; ++t) wreg[t] = Wb[(size_t)t * CO + co];

    int s = 0, s2 = 0;
    for (int wo = 0; wo < WO; ++wo) {
        int wbase = 2 * wo - 1;
        int cm0 = (wo > 0) ? -1 : 0;
        int cm3 = (wo < WO - 1) ? -1 : 0;
        int iwc[4];
        #pragma unroll
        for (int c = 0; c < 4; ++c) {
            int iw = wbase + c;
            iwc[c] = iw < 0 ? 0 : (iw > WI - 1 ? WI - 1 : iw);
        }
        int q[4];
        #pragma unroll
        for (int i = 0; i < 4; ++i) q[i] = 0;

        #pragma unroll
        for (int ch = 0; ch < CH; ++ch) {
            u64 tx[4][4], ty[4][4];
            #pragma unroll
            for (int r = 0; r < 4; ++r) {
                #pragma unroll
                for (int c = 0; c < 4; ++c) {
                    const ulonglong2* p =
                        (const ulonglong2*)(rowp[r] + (size_t)iwc[c] * CW + 2 * ch);
                    ulonglong2 v = *p;
                    tx[r][c] = v.x; ty[r][c] = v.y;
                }
            }
            #pragma unroll
            for (int py = 0; py < 2; ++py) {
                #pragma unroll
                for (int px = 0; px < 2; ++px) {
                    int qq = 0;
                    #pragma unroll
                    for (int kh = 0; kh < 3; ++kh) {
                        #pragma unroll
                        for (int kw = 0; kw < 3; ++kw) {
                            int r = py + kh, c = px + kw;
                            int add = __popcll(tx[r][c] ^ wreg[(kh * 3 + kw) * CW + 2 * ch])
                                    + __popcll(ty[r][c] ^ wreg[(kh * 3 + kw) * CW + 2 * ch + 1]);
                            int m = rmask[r] & (c == 0 ? cm0 : (c == 3 ? cm3 : -1));
                            qq += add & m;
                        }
                    }
                    q[py * 2 + px] += qq;
                }
            }
        }
        int best = -(1 << 30);
        #pragma unroll
        for (int py = 0; py < 2; ++py) {
            #pragma unroll
            for (int px = 0; px < 2; ++px) {
                int hc = 2 * ho + py, wc = 2 * wo + px;
                int vr = 3 - (hc == 0) - (hc == HI - 1);
                int vc = 3 - (wc == 0) - (wc == WI - 1);
                int dot = vr * vc * CW * 64 - 2 * q[py * 2 + px];
                best = dot > best ? dot : best;
            }
        }
        dots[(size_t)((n * HO + ho) * WO + wo) * CO + co] = (short)best;
        s += best;
        s2 += best * best;
    }
    atomicAdd((u64*)&sums[co], (u64)(i64)s);
    atomicAdd((u64*)&sums[CO + co], (u64)(i64)s2);
}

__global__ void finalize_bn(const i64* __restrict__ sums,
                            const float* __restrict__ g, const float* __restrict__ b,
                            int CO, double cnt, double* __restrict__ M,
                            double* __restrict__ A, double* __restrict__ BB) {
    int c = blockIdx.x * blockDim.x + threadIdx.x;
    if (c >= CO) return;
    double m = (double)sums[c] / cnt;
    double var = (double)sums[CO + c] / cnt - m * m;
    M[c]  = m;
    A[c]  = (double)g[c] / sqrt(var + 1e-5);
    BB[c] = (double)b[c];
}

// ---------------------------------------------------------------- binarize + bit-pack
template <int CO>
__global__ __launch_bounds__(256) void binpack_k(const short* __restrict__ xin,
                                                 const double* __restrict__ M,
                                                 const double* __restrict__ A,
                                                 const double* __restrict__ BB,
                                                 u64* __restrict__ Ab) {
    constexpr int CWo = CO / 64;
    int widx = blockIdx.x * 4 + (threadIdx.x >> 6);
    int lane = threadIdx.x & 63;
    int w = widx & (CWo - 1);
    int p = widx / CWo;
    int c = (w << 6) | lane;
    double t = A[c] * ((double)xin[(size_t)p * CO + c] - M[c]) + BB[c];
    u64 m = __ballot(t > 0.0);
    if (lane == 0) Ab[widx] = m;
}

// ---------------------------------------------------------------- FC head
__global__ __launch_bounds__(256) void fc_k(const short* __restrict__ x5,
                                            const double* __restrict__ M,
                                            const double* __restrict__ A,
                                            const double* __restrict__ BB,
                                            const float* __restrict__ wfc,
                                            const float* __restrict__ bfc,
                                            float* __restrict__ out) {
    int n = blockIdx.x / 10, k = blockIdx.x % 10;
    double acc = 0.0;
    for (int i = threadIdx.x; i < 8192; i += 256) {
        int c = i >> 4, hw = i & 15, h = hw >> 2, ww = hw & 3;
        double t = A[c] * ((double)x5[(size_t)((n * 4 + h) * 4 + ww) * 512 + c] - M[c]) + BB[c];
        t = t < -1.0 ? -1.0 : (t > 1.0 ? 1.0 : t);
        acc += t * (double)wfc[(size_t)k * 8192 + i];
    }
    acc = waveRed(acc);
    __shared__ double sd[4];
    if ((threadIdx.x & 63) == 0) sd[threadIdx.x >> 6] = acc;
    __syncthreads();
    if (threadIdx.x == 0)
        out[n * 10 + k] = (float)(sd[0] + sd[1] + sd[2] + sd[3] + (double)bfc[k]);
}

// ---------------------------------------------------------------- launch
extern "C" void kernel_launch(void* const* d_in, const int* in_sizes, int n_in,
                              void* d_out, int out_size, void* d_ws, size_t ws_size,
                              hipStream_t stream) {
    (void)in_sizes; (void)n_in; (void)out_size; (void)ws_size;

    const float* x   = (const float*)d_in[0];
    const float* w0  = (const float*)d_in[1];
    const float* g0  = (const float*)d_in[2];
    const float* b0  = (const float*)d_in[3];
    const float* w1  = (const float*)d_in[4];
    const float* g1  = (const float*)d_in[5];
    const float* b1  = (const float*)d_in[6];
    const float* w2  = (const float*)d_in[7];
    const float* g2  = (const float*)d_in[8];
    const float* b2  = (const float*)d_in[9];
    const float* w3  = (const float*)d_in[10];
    const float* g3  = (const float*)d_in[11];
    const float* b3  = (const float*)d_in[12];
    const float* w4  = (const float*)d_in[13];
    const float* g4  = (const float*)d_in[14];
    const float* b4  = (const float*)d_in[15];
    const float* w5  = (const float*)d_in[16];
    const float* g5  = (const float*)d_in[17];
    const float* b5  = (const float*)d_in[18];
    const float* wfc = (const float*)d_in[19];
    const float* bfc = (const float*)d_in[20];
    float* out = (float*)d_out;

    // ---- workspace layout (~43.2 MB) ----
    char* ws = (char*)d_ws;
    double* sum0   = (double*)ws;                  // 128
    double* sumsq0 = sum0 + 128;                   // 128
    i64* isums = (i64*)(sumsq0 + 128);             // 5 layers * 1024
    // zero span: 2048 + 40960 = 43008 bytes
    double* M  = (double*)(ws + 65536);            // 6*512
    double* A  = M + 3072;
    double* BB = A + 3072;
    char* p = ws + 65536 + 73728;
    u64* A0 = (u64*)p;  p += (size_t)262144 * 2 * 8;   // 4 MiB
    u64* A1 = (u64*)p;  p += (size_t)65536 * 2 * 8;    // 1 MiB
    u64* A2 = (u64*)p;  p += (size_t)65536 * 4 * 8;    // 2 MiB
    u64* A3 = (u64*)p;  p += (size_t)16384 * 4 * 8;    // 0.5 MiB
    u64* A4 = (u64*)p;  p += (size_t)16384 * 8 * 8;    // 1 MiB
    u64* Wb1 = (u64*)p; p += 2304 * 8;
    u64* Wb2 = (u64*)p; p += 4608 * 8;
    u64* Wb3 = (u64*)p; p += 9216 * 8;
    u64* Wb4 = (u64*)p; p += 18432 * 8;
    u64* Wb5 = (u64*)p; p += 36864 * 8;
    p = (char*)(((uintptr_t)p + 255) & ~(uintptr_t)255);
    short* dots = (short*)p;                       // max 65536*256*2 = 33.5 MB

    hipMemsetAsync(d_ws, 0, 43008, stream);

    // weight bit-packs
    pack_w<<<576,  256, 0, stream>>>(w1, Wb1, 128, 128);
    pack_w<<<1152, 256, 0, stream>>>(w2, Wb2, 128, 256);
    pack_w<<<2304, 256, 0, stream>>>(w3, Wb3, 256, 256);
    pack_w<<<4608, 256, 0, stream>>>(w4, Wb4, 256, 512);
    pack_w<<<9216, 256, 0, stream>>>(w5, Wb5, 512, 512);

    // conv0 (np-f32 FMA (kh,kw,ci)) + BN0 + pack
    conv0_sums3<<<dim3(4, 256), 256, 0, stream>>>(x, w0, sum0, sumsq0);
    finalize_c0<<<1, 128, 0, stream>>>(sum0, sumsq0, g0, b0, M, A, BB);
    conv0_pack3<<<1024, 256, 0, stream>>>(x, w0, M, A, BB, A0);

    // L1: 128->128 @32x32, pool -> 16x16  (window-shared pooled kernel)
    bconv_pool<2, 128, 32><<<2048, 256, 0, stream>>>(A0, Wb1, dots, isums);
    finalize_bn<<<1, 128, 0, stream>>>(isums, g1, b1, 128, 65536.0, M + 512, A + 512, BB + 512);
    binpack_k<128><<<32768, 256, 0, stream>>>(dots, M + 512, A + 512, BB + 512, A1);

    // L2: 128->256 @16x16 (R11 kernel)
    bconv_bits3<2, 256, 16, false><<<4096, 256, 0, stream>>>(A1, Wb2, dots, isums + 1024);
    finalize_bn<<<1, 256, 0, stream>>>(isums + 1024, g2, b2, 256, 65536.0, M + 1024, A + 1024, BB + 1024);
    binpack_k<256><<<65536, 256, 0, stream>>>(dots, M + 1024, A + 1024, BB + 1024, A2);

    // L3: 256->256 @16x16, pool -> 8x8  (window-shared pooled kernel)
    bconv_pool<4, 256, 16><<<2048, 256, 0, stream>>>(A2, Wb3, dots, isums + 2048);
    finalize_bn<<<1, 256, 0, stream>>>(isums + 2048, g3, b3, 256, 16384.0, M + 1536, A + 1536, BB + 1536);
    binpack_k<256><<<16384, 256, 0, stream>>>(dots, M + 1536, A + 1536, BB + 1536, A3);

    // L4: 256->512 @8x8 (R11 kernel)
    bconv_bits3<4, 512, 8, false><<<4096, 256, 0, stream>>>(A3, Wb4, dots, isums + 3072);
    finalize_bn<<<1, 512, 0, stream>>>(isums + 3072, g4, b4, 512, 16384.0, M + 2048, A + 2048, BB + 2048);
    binpack_k<512><<<32768, 256, 0, stream>>>(dots, M + 2048, A + 2048, BB + 2048, A4);

    // L5: 512->512 @8x8, pool -> 4x4 (R11 kernel)
    bconv_bits3<8, 512, 8, true><<<2048, 256, 0, stream>>>(A4, Wb5, dots, isums + 4096);
    finalize_bn<<<1, 512, 0, stream>>>(isums + 4096, g5, b5, 512, 4096.0, M + 2560, A + 2560, BB + 2560);

    // FC head
    fc_k<<<2560, 256, 0, stream>>>(dots, M + 2560, A + 2560, BB + 2560, wfc, bfc, out);
}